// Round 1
// baseline (519.787 us; speedup 1.0000x reference)
//
#include <hip/hip_runtime.h>
#include <stdint.h>

// ---------- helpers ----------
typedef short v8s __attribute__((ext_vector_type(8)));
typedef float v4f __attribute__((ext_vector_type(4)));

__device__ inline float bf2f(unsigned short h) {
    union { unsigned u; float f; } c; c.u = ((unsigned)h) << 16; return c.f;
}
__device__ inline unsigned short f2bf(float f) {
    union { float f; unsigned u; } c; c.f = f;
    unsigned u = c.u;
    unsigned r = (u + 0x7FFFu + ((u >> 16) & 1u)) >> 16;  // RNE
    return (unsigned short)r;
}
__device__ inline void gl_lds16(const unsigned short* g, unsigned short* l) {
    __builtin_amdgcn_global_load_lds(
        (const __attribute__((address_space(1))) unsigned int*)(g),
        (__attribute__((address_space(3))) unsigned int*)(l), 16, 0, 0);
}

// ---------- graph preprocessing ----------
__global__ void k_count(const int* __restrict__ dst, int E, int* __restrict__ cnt) {
    int e = blockIdx.x * 256 + threadIdx.x;
    if (e < E) atomicAdd(&cnt[dst[e]], 1);
}

__global__ void k_dinv(const int* __restrict__ cnt, int n, float* __restrict__ dinv) {
    int i = blockIdx.x * 256 + threadIdx.x;
    if (i < n) dinv[i] = rsqrtf((float)(cnt[i] + 1));  // +1 self loop; deg>=1 always
}

__global__ void k_scan1(const int* __restrict__ cnt, int n, int* __restrict__ incl,
                        int* __restrict__ bsum) {
    __shared__ int sm[256];
    int t = threadIdx.x;
    int i = blockIdx.x * 256 + t;
    int v = (i < n) ? cnt[i] : 0;
    sm[t] = v; __syncthreads();
    for (int off = 1; off < 256; off <<= 1) {
        int add = (t >= off) ? sm[t - off] : 0;
        __syncthreads();
        sm[t] += add;
        __syncthreads();
    }
    if (i < n) incl[i] = sm[t];
    if (t == 255) bsum[blockIdx.x] = sm[255];
}

__global__ void k_scan2(const int* __restrict__ bsum, int nb, int* __restrict__ boff) {
    __shared__ int sm[256];
    int t = threadIdx.x;
    int v = (t < nb) ? bsum[t] : 0;
    sm[t] = v; __syncthreads();
    for (int off = 1; off < 256; off <<= 1) {
        int add = (t >= off) ? sm[t - off] : 0;
        __syncthreads();
        sm[t] += add;
        __syncthreads();
    }
    if (t < nb) boff[t] = sm[t] - v;  // exclusive
}

__global__ void k_scan3(const int* __restrict__ cnt, int n, const int* __restrict__ boff,
                        int* __restrict__ rs) {
    int i = blockIdx.x * 256 + threadIdx.x;
    if (i < n) rs[i] = rs[i] + boff[blockIdx.x] - cnt[i];  // inclusive -> exclusive global
}

__global__ void k_scatter(const int* __restrict__ src, const int* __restrict__ dst, int E,
                          const int* __restrict__ rs, int* __restrict__ cursor,
                          int* __restrict__ col) {
    int e = blockIdx.x * 256 + threadIdx.x;
    if (e < E) {
        int d = dst[e];
        int p = rs[d] + atomicAdd(&cursor[d], 1);
        col[p] = src[e];
    }
}

// ---------- dtype conversion ----------
// x fp32 [n,256] -> bf16 [mpad,256], zero-padded rows
__global__ void k_cvt_x(const float* __restrict__ x, unsigned short* __restrict__ A,
                        int n, int mpad) {
    int g = blockIdx.x * 256 + threadIdx.x;  // one float4 group
    int total = mpad * 64;
    if (g >= total) return;
    int row = g >> 6;
    float4 v;
    if (row < n) v = ((const float4*)x)[(size_t)g];
    else v = make_float4(0.f, 0.f, 0.f, 0.f);
    ushort4 o;
    o.x = f2bf(v.x); o.y = f2bf(v.y); o.z = f2bf(v.z); o.w = f2bf(v.w);
    ((ushort4*)A)[(size_t)g] = o;
}

// W [K=256, N] fp32 -> Wt [N, 256] bf16 (transposed for LDS-friendly B staging)
__global__ void k_cvt_w(const float* __restrict__ W, unsigned short* __restrict__ Wt,
                        int K, int N) {
    int idx = blockIdx.x * 256 + threadIdx.x;
    if (idx >= K * N) return;
    int nn = idx >> 8;       // K = 256
    int k = idx & 255;
    Wt[idx] = f2bf(W[(size_t)k * N + nn]);
}

// ---------- GEMM: Hs[m,n] = dinv[m] * sum_k A[m,k] * W[k,n] ----------
// A bf16 [mpad,256], Wt bf16 [N,256] (row n holds W[:,n]), Hs bf16 [mpad,N]
__launch_bounds__(256, 2)
__global__ void k_gemm(const unsigned short* __restrict__ A,
                       const unsigned short* __restrict__ Wt,
                       unsigned short* __restrict__ Hs,
                       const float* __restrict__ dinv, int n, int N) {
    __shared__ unsigned short sA[128 * 32];
    __shared__ unsigned short sB[128 * 32];
    const int t = threadIdx.x;
    const int lane = t & 63;
    const int wave = t >> 6;
    const int wm = wave >> 1, wn = wave & 1;
    const int m0 = blockIdx.x * 128;
    const int n0 = blockIdx.y * 128;

    v4f acc[4][4];
#pragma unroll
    for (int i = 0; i < 4; i++)
#pragma unroll
        for (int j = 0; j < 4; j++)
#pragma unroll
            for (int r = 0; r < 4; r++) acc[i][j][r] = 0.f;

    const int c0 = t, c1 = t + 256;
    const int r0 = c0 >> 2, kc0 = (c0 & 3) * 8;
    const int r1 = c1 >> 2, kc1 = (c1 & 3) * 8;
    const size_t aBase0 = (size_t)(m0 + r0) * 256 + kc0;
    const size_t aBase1 = (size_t)(m0 + r1) * 256 + kc1;
    const size_t bBase0 = (size_t)(n0 + r0) * 256 + kc0;
    const size_t bBase1 = (size_t)(n0 + r1) * 256 + kc1;

    const int q = lane >> 4;
    const int lm = lane & 15;

    for (int k0 = 0; k0 < 256; k0 += 32) {
        __syncthreads();  // protect LDS from previous iter's readers
        gl_lds16(A + aBase0 + k0, &sA[c0 * 8]);
        gl_lds16(A + aBase1 + k0, &sA[c1 * 8]);
        gl_lds16(Wt + bBase0 + k0, &sB[c0 * 8]);
        gl_lds16(Wt + bBase1 + k0, &sB[c1 * 8]);
        __syncthreads();  // drain global_load_lds (vmcnt) + barrier

        v8s afr[4], bfr[4];
#pragma unroll
        for (int i = 0; i < 4; i++) {
            int r = wm * 64 + i * 16 + lm;
            afr[i] = *(const v8s*)&sA[r * 32 + q * 8];
        }
#pragma unroll
        for (int j = 0; j < 4; j++) {
            int nn = wn * 64 + j * 16 + lm;
            bfr[j] = *(const v8s*)&sB[nn * 32 + q * 8];
        }
#pragma unroll
        for (int i = 0; i < 4; i++)
#pragma unroll
            for (int j = 0; j < 4; j++)
                acc[i][j] = __builtin_amdgcn_mfma_f32_16x16x32_bf16(afr[i], bfr[j],
                                                                    acc[i][j], 0, 0, 0);
    }

    // epilogue: C/D layout col=lane&15, row=(lane>>4)*4+reg
#pragma unroll
    for (int i = 0; i < 4; i++) {
        int mbase = m0 + wm * 64 + i * 16 + q * 4;
#pragma unroll
        for (int r = 0; r < 4; r++) {
            int m = mbase + r;
            float s = (m < n) ? dinv[m] : 0.f;
#pragma unroll
            for (int j = 0; j < 4; j++) {
                int colI = n0 + wn * 64 + j * 16 + lm;
                Hs[(size_t)m * N + colI] = f2bf(acc[i][j][r] * s);
            }
        }
    }
}

// ---------- aggregation: out[i] = act(dinv[i]*(sum_{nbr} hs[src] + hs[i]) + b) ----------
template <int D, bool RELU, bool F32OUT>
__launch_bounds__(256, 4)
__global__ void k_agg(const unsigned short* __restrict__ Hs,
                      const int* __restrict__ rs, const int* __restrict__ cnt,
                      const int* __restrict__ col, const float* __restrict__ dinv,
                      const float* __restrict__ bias,
                      unsigned short* __restrict__ outb, float* __restrict__ outf, int n) {
    const int lane = threadIdx.x & 63;
    const int i = blockIdx.x * 4 + (threadIdx.x >> 6);
    if (i >= n) return;
    constexpr int VPL = D / 64;  // floats per lane: 4 (D=256) or 2 (D=128)
    float acc[VPL];
#pragma unroll
    for (int k = 0; k < VPL; k++) acc[k] = 0.f;

    auto accum = [&](int c) {
        const unsigned* q = (const unsigned*)(Hs + (size_t)c * D) + lane * (VPL / 2);
        if constexpr (VPL == 4) {
            uint2 v = *(const uint2*)q;
            acc[0] += bf2f((unsigned short)(v.x & 0xffffu));
            acc[1] += bf2f((unsigned short)(v.x >> 16));
            acc[2] += bf2f((unsigned short)(v.y & 0xffffu));
            acc[3] += bf2f((unsigned short)(v.y >> 16));
        } else {
            unsigned v = *q;
            acc[0] += bf2f((unsigned short)(v & 0xffffu));
            acc[1] += bf2f((unsigned short)(v >> 16));
        }
    };

    accum(i);  // self loop
    int s = rs[i], e = s + cnt[i];
    for (int p = s; p < e; ++p) accum(col[p]);

    float di = dinv[i];
    if constexpr (F32OUT) {
        float2 o;
        o.x = di * acc[0] + bias[lane * 2 + 0];
        o.y = di * acc[1] + bias[lane * 2 + 1];
        if (RELU) { o.x = fmaxf(o.x, 0.f); o.y = fmaxf(o.y, 0.f); }
        *(float2*)(outf + (size_t)i * D + lane * 2) = o;
    } else {
        float t0 = di * acc[0] + bias[lane * 4 + 0];
        float t1 = di * acc[1] + bias[lane * 4 + 1];
        float t2 = di * acc[2] + bias[lane * 4 + 2];
        float t3 = di * acc[3] + bias[lane * 4 + 3];
        if (RELU) {
            t0 = fmaxf(t0, 0.f); t1 = fmaxf(t1, 0.f);
            t2 = fmaxf(t2, 0.f); t3 = fmaxf(t3, 0.f);
        }
        ushort4 o;
        o.x = f2bf(t0); o.y = f2bf(t1); o.z = f2bf(t2); o.w = f2bf(t3);
        *(ushort4*)(outb + (size_t)i * D + lane * 4) = o;
    }
}

// ---------- launch ----------
extern "C" void kernel_launch(void* const* d_in, const int* in_sizes, int n_in,
                              void* d_out, int out_size, void* d_ws, size_t ws_size,
                              hipStream_t stream) {
    const float* x  = (const float*)d_in[0];
    const int*   ei = (const int*)d_in[1];   // [2, E] int32 (harness converts integers)
    const float* W1 = (const float*)d_in[2];
    const float* b1 = (const float*)d_in[3];
    const float* W2 = (const float*)d_in[4];
    const float* b2 = (const float*)d_in[5];
    const float* W3 = (const float*)d_in[6];
    const float* b3 = (const float*)d_in[7];

    const int n = in_sizes[0] / 256;     // 50000
    const int E = in_sizes[1] / 2;       // 800000
    const int mpad = ((n + 127) / 128) * 128;  // 50048

    char* ws = (char*)d_ws;
    size_t off = 0;
    auto alloc = [&](size_t bytes) -> void* {
        void* p = ws + off;
        off += (bytes + 255) & ~(size_t)255;
        return p;
    };
    int* cnt      = (int*)alloc((size_t)n * 4);
    int* cursor   = (int*)alloc((size_t)n * 4);
    int* rs       = (int*)alloc((size_t)n * 4);
    float* dinv   = (float*)alloc((size_t)n * 4);
    int* bsum     = (int*)alloc(256 * 4);
    int* boff     = (int*)alloc(256 * 4);
    int* col      = (int*)alloc((size_t)E * 4);
    unsigned short* W1t = (unsigned short*)alloc(256 * 256 * 2);
    unsigned short* W2t = (unsigned short*)alloc(256 * 256 * 2);
    unsigned short* W3t = (unsigned short*)alloc(128 * 256 * 2);
    unsigned short* bufA = (unsigned short*)alloc((size_t)mpad * 256 * 2);
    unsigned short* bufB = (unsigned short*)alloc((size_t)mpad * 256 * 2);
    (void)ws_size; (void)n_in; (void)out_size;

    const int* srcp = ei;
    const int* dstp = ei + E;
    const int gE = (E + 255) / 256;
    const int gN = (n + 255) / 256;

    hipMemsetAsync(cnt, 0, (size_t)n * 4, stream);
    hipMemsetAsync(cursor, 0, (size_t)n * 4, stream);

    k_count<<<gE, 256, 0, stream>>>(dstp, E, cnt);
    k_dinv<<<gN, 256, 0, stream>>>(cnt, n, dinv);
    k_scan1<<<gN, 256, 0, stream>>>(cnt, n, rs, bsum);
    k_scan2<<<1, 256, 0, stream>>>(bsum, gN, boff);
    k_scan3<<<gN, 256, 0, stream>>>(cnt, n, boff, rs);
    k_scatter<<<gE, 256, 0, stream>>>(srcp, dstp, E, rs, cursor, col);

    k_cvt_x<<<(mpad * 64 + 255) / 256, 256, 0, stream>>>(x, bufA, n, mpad);
    k_cvt_w<<<(256 * 256 + 255) / 256, 256, 0, stream>>>(W1, W1t, 256, 256);
    k_cvt_w<<<(256 * 256 + 255) / 256, 256, 0, stream>>>(W2, W2t, 256, 256);
    k_cvt_w<<<(256 * 128 + 255) / 256, 256, 0, stream>>>(W3, W3t, 256, 128);

    const int gAgg = (n + 3) / 4;
    dim3 gg1(mpad / 128, 2);
    k_gemm<<<gg1, 256, 0, stream>>>(bufA, W1t, bufB, dinv, n, 256);
    k_agg<256, true, false><<<gAgg, 256, 0, stream>>>(bufB, rs, cnt, col, dinv, b1,
                                                      bufA, nullptr, n);
    k_gemm<<<gg1, 256, 0, stream>>>(bufA, W2t, bufB, dinv, n, 256);
    k_agg<256, true, false><<<gAgg, 256, 0, stream>>>(bufB, rs, cnt, col, dinv, b2,
                                                      bufA, nullptr, n);
    dim3 gg3(mpad / 128, 1);
    k_gemm<<<gg3, 256, 0, stream>>>(bufA, W3t, bufB, dinv, n, 128);
    k_agg<128, false, true><<<gAgg, 256, 0, stream>>>(bufB, rs, cnt, col, dinv, b3,
                                                      nullptr, (float*)d_out, n);
}

// Round 2
// 397.347 us; speedup vs baseline: 1.3081x; 1.3081x over previous
//
#include <hip/hip_runtime.h>
#include <stdint.h>

// ---------- helpers ----------
typedef short v8s __attribute__((ext_vector_type(8)));
typedef float v4f __attribute__((ext_vector_type(4)));

__device__ inline float bf2f(unsigned short h) {
    union { unsigned u; float f; } c; c.u = ((unsigned)h) << 16; return c.f;
}
__device__ inline unsigned short f2bf(float f) {
    union { float f; unsigned u; } c; c.f = f;
    unsigned u = c.u;
    unsigned r = (u + 0x7FFFu + ((u >> 16) & 1u)) >> 16;  // RNE
    return (unsigned short)r;
}
__device__ inline void gl_lds16(const unsigned short* g, unsigned short* l) {
    __builtin_amdgcn_global_load_lds(
        (const __attribute__((address_space(1))) unsigned int*)(g),
        (__attribute__((address_space(3))) unsigned int*)(l), 16, 0, 0);
}

// ---------- graph preprocessing ----------
__global__ void k_count(const int* __restrict__ dst, int E, int* __restrict__ cnt) {
    int e = blockIdx.x * 256 + threadIdx.x;
    if (e < E) atomicAdd(&cnt[dst[e]], 1);
}

__global__ void k_scan1(const int* __restrict__ cnt, int n, int* __restrict__ incl,
                        int* __restrict__ bsum) {
    __shared__ int sm[256];
    int t = threadIdx.x;
    int i = blockIdx.x * 256 + t;
    int v = (i < n) ? cnt[i] : 0;
    sm[t] = v; __syncthreads();
    for (int off = 1; off < 256; off <<= 1) {
        int add = (t >= off) ? sm[t - off] : 0;
        __syncthreads();
        sm[t] += add;
        __syncthreads();
    }
    if (i < n) incl[i] = sm[t];
    if (t == 255) bsum[blockIdx.x] = sm[255];
}

__global__ void k_scan2(const int* __restrict__ bsum, int nb, int* __restrict__ boff) {
    __shared__ int sm[256];
    int t = threadIdx.x;
    int v = (t < nb) ? bsum[t] : 0;
    sm[t] = v; __syncthreads();
    for (int off = 1; off < 256; off <<= 1) {
        int add = (t >= off) ? sm[t - off] : 0;
        __syncthreads();
        sm[t] += add;
        __syncthreads();
    }
    if (t < nb) boff[t] = sm[t] - v;  // exclusive
}

// inclusive->exclusive global scan; also computes dinv (fused former k_dinv)
__global__ void k_scan3(const int* __restrict__ cnt, int n, const int* __restrict__ boff,
                        int* __restrict__ rs, float* __restrict__ dinv) {
    int i = blockIdx.x * 256 + threadIdx.x;
    if (i < n) {
        int c = cnt[i];
        rs[i] = rs[i] + boff[blockIdx.x] - c;
        dinv[i] = rsqrtf((float)(c + 1));  // +1 self loop; deg>=1 always
    }
}

__global__ void k_scatter(const int* __restrict__ src, const int* __restrict__ dst, int E,
                          const int* __restrict__ rs, int* __restrict__ cursor,
                          int* __restrict__ col) {
    int e = blockIdx.x * 256 + threadIdx.x;
    if (e < E) {
        int d = dst[e];
        int p = rs[d] + atomicAdd(&cursor[d], 1);
        col[p] = src[e];
    }
}

// ---------- dtype conversion ----------
// x fp32 [n,256] -> bf16 [mpad,256], zero-padded rows
__global__ void k_cvt_x(const float* __restrict__ x, unsigned short* __restrict__ A,
                        int n, int mpad) {
    int g = blockIdx.x * 256 + threadIdx.x;  // one float4 group
    int total = mpad * 64;
    if (g >= total) return;
    int row = g >> 6;
    float4 v;
    if (row < n) v = ((const float4*)x)[(size_t)g];
    else v = make_float4(0.f, 0.f, 0.f, 0.f);
    ushort4 o;
    o.x = f2bf(v.x); o.y = f2bf(v.y); o.z = f2bf(v.z); o.w = f2bf(v.w);
    ((ushort4*)A)[(size_t)g] = o;
}

// all three weights -> transposed bf16, one dispatch.
// layout in Wt: [0,65536) W1t, [65536,131072) W2t, [131072,163840) W3t
__global__ void k_cvt_w3(const float* __restrict__ W1, const float* __restrict__ W2,
                         const float* __restrict__ W3, unsigned short* __restrict__ Wt) {
    int idx = blockIdx.x * 256 + threadIdx.x;  // < 163840
    const float* W; int base, N;
    if (idx < 65536)       { W = W1; base = 0;      N = 256; }
    else if (idx < 131072) { W = W2; base = 65536;  N = 256; }
    else                   { W = W3; base = 131072; N = 128; }
    int loc = idx - base;
    int nn = loc >> 8;   // K = 256
    int k = loc & 255;
    Wt[idx] = f2bf(W[(size_t)k * N + nn]);
}

// ---------- GEMM: Hs[m,n] = dinv[m] * sum_k A[m,k] * W[k,n] ----------
__launch_bounds__(256, 2)
__global__ void k_gemm(const unsigned short* __restrict__ A,
                       const unsigned short* __restrict__ Wt,
                       unsigned short* __restrict__ Hs,
                       const float* __restrict__ dinv, int n, int N) {
    __shared__ unsigned short sA[128 * 32];
    __shared__ unsigned short sB[128 * 32];
    const int t = threadIdx.x;
    const int lane = t & 63;
    const int wave = t >> 6;
    const int wm = wave >> 1, wn = wave & 1;
    const int m0 = blockIdx.x * 128;
    const int n0 = blockIdx.y * 128;

    v4f acc[4][4];
#pragma unroll
    for (int i = 0; i < 4; i++)
#pragma unroll
        for (int j = 0; j < 4; j++)
#pragma unroll
            for (int r = 0; r < 4; r++) acc[i][j][r] = 0.f;

    const int c0 = t, c1 = t + 256;
    const int r0 = c0 >> 2, kc0 = (c0 & 3) * 8;
    const int r1 = c1 >> 2, kc1 = (c1 & 3) * 8;
    const size_t aBase0 = (size_t)(m0 + r0) * 256 + kc0;
    const size_t aBase1 = (size_t)(m0 + r1) * 256 + kc1;
    const size_t bBase0 = (size_t)(n0 + r0) * 256 + kc0;
    const size_t bBase1 = (size_t)(n0 + r1) * 256 + kc1;

    const int q = lane >> 4;
    const int lm = lane & 15;

    for (int k0 = 0; k0 < 256; k0 += 32) {
        __syncthreads();
        gl_lds16(A + aBase0 + k0, &sA[c0 * 8]);
        gl_lds16(A + aBase1 + k0, &sA[c1 * 8]);
        gl_lds16(Wt + bBase0 + k0, &sB[c0 * 8]);
        gl_lds16(Wt + bBase1 + k0, &sB[c1 * 8]);
        __syncthreads();

        v8s afr[4], bfr[4];
#pragma unroll
        for (int i = 0; i < 4; i++) {
            int r = wm * 64 + i * 16 + lm;
            afr[i] = *(const v8s*)&sA[r * 32 + q * 8];
        }
#pragma unroll
        for (int j = 0; j < 4; j++) {
            int nn = wn * 64 + j * 16 + lm;
            bfr[j] = *(const v8s*)&sB[nn * 32 + q * 8];
        }
#pragma unroll
        for (int i = 0; i < 4; i++)
#pragma unroll
            for (int j = 0; j < 4; j++)
                acc[i][j] = __builtin_amdgcn_mfma_f32_16x16x32_bf16(afr[i], bfr[j],
                                                                    acc[i][j], 0, 0, 0);
    }

    // epilogue: C/D layout col=lane&15, row=(lane>>4)*4+reg
#pragma unroll
    for (int i = 0; i < 4; i++) {
        int mbase = m0 + wm * 64 + i * 16 + q * 4;
#pragma unroll
        for (int r = 0; r < 4; r++) {
            int m = mbase + r;
            float s = (m < n) ? dinv[m] : 0.f;
#pragma unroll
            for (int j = 0; j < 4; j++) {
                int colI = n0 + wn * 64 + j * 16 + lm;
                Hs[(size_t)m * N + colI] = f2bf(acc[i][j][r] * s);
            }
        }
    }
}

// ---------- aggregation: out[i] = act(dinv[i]*(sum_{nbr} hs[src] + hs[i]) + b) ----------
// Latency-optimized: coalesced adjacency chunk load + shfl broadcast of indices,
// 16B/lane gathers packing NPG neighbors per wave-load, 2x unrolled (independent
// loads in flight), shfl_xor cross-slot reduce, single vector store.
template <int D, bool RELU, bool F32OUT>
__launch_bounds__(256, 8)
__global__ void k_agg(const unsigned short* __restrict__ Hs,
                      const int* __restrict__ rs, const int* __restrict__ cnt,
                      const int* __restrict__ col, const float* __restrict__ dinv,
                      const float* __restrict__ bias,
                      unsigned short* __restrict__ outb, float* __restrict__ outf,
                      int n, int nzero) {
    constexpr int LPN = D / 8;     // lanes per neighbor row (32 for D=256, 16 for D=128)
    constexpr int NPG = 64 / LPN;  // neighbors per gather instruction (2 or 4)
    const int lane = threadIdx.x & 63;
    const int i = blockIdx.x * 4 + (threadIdx.x >> 6);
    if (i >= n) return;
    const int g = lane / LPN;      // neighbor slot within the gather
    const int cl = lane % LPN;     // channel chunk (8 channels each)

    float acc[8];
#pragma unroll
    for (int k = 0; k < 8; k++) acc[k] = 0.f;

    auto acc8 = [&](uint4 q) {
        acc[0] += bf2f((unsigned short)(q.x & 0xffffu));
        acc[1] += bf2f((unsigned short)(q.x >> 16));
        acc[2] += bf2f((unsigned short)(q.y & 0xffffu));
        acc[3] += bf2f((unsigned short)(q.y >> 16));
        acc[4] += bf2f((unsigned short)(q.z & 0xffffu));
        acc[5] += bf2f((unsigned short)(q.z >> 16));
        acc[6] += bf2f((unsigned short)(q.w & 0xffffu));
        acc[7] += bf2f((unsigned short)(q.w >> 16));
    };

    const int s = rs[i], deg = cnt[i];
    const int T = deg + 1;                       // self + neighbors
    const int Tpad = (T + NPG - 1) & ~(NPG - 1); // pad with zero-row nzero

    for (int b = 0; b < Tpad; b += 64) {
        int t = b + lane;
        int v;
        if (t == 0) v = i;                       // self loop
        else if (t <= deg) v = col[s + t - 1];   // coalesced chunk load
        else v = nzero;                          // zero row pad
        int lim = min(64, Tpad - b);
        int t2 = 0;
        for (; t2 + 2 * NPG <= lim; t2 += 2 * NPG) {
            int c0 = __shfl(v, t2 + g);
            int c1 = __shfl(v, t2 + NPG + g);
            uint4 q0 = *(const uint4*)(Hs + (size_t)c0 * D + cl * 8);
            uint4 q1 = *(const uint4*)(Hs + (size_t)c1 * D + cl * 8);
            acc8(q0);
            acc8(q1);
        }
        if (t2 < lim) {
            int c0 = __shfl(v, t2 + g);
            uint4 q0 = *(const uint4*)(Hs + (size_t)c0 * D + cl * 8);
            acc8(q0);
        }
    }

    // reduce across neighbor slots: after this every lane holds the full sum
#pragma unroll
    for (int off = LPN; off < 64; off <<= 1) {
#pragma unroll
        for (int k = 0; k < 8; k++) acc[k] += __shfl_xor(acc[k], off);
    }

    if (g == 0) {  // lanes 0..LPN-1 write
        float di = dinv[i];
        float o[8];
#pragma unroll
        for (int k = 0; k < 8; k++) {
            o[k] = di * acc[k] + bias[cl * 8 + k];
            if (RELU) o[k] = fmaxf(o[k], 0.f);
        }
        if constexpr (F32OUT) {
            float4 a = make_float4(o[0], o[1], o[2], o[3]);
            float4 b = make_float4(o[4], o[5], o[6], o[7]);
            float* p = outf + (size_t)i * D + cl * 8;
            *(float4*)p = a;
            *(float4*)(p + 4) = b;
        } else {
            uint4 q;
            q.x = ((unsigned)f2bf(o[1]) << 16) | f2bf(o[0]);
            q.y = ((unsigned)f2bf(o[3]) << 16) | f2bf(o[2]);
            q.z = ((unsigned)f2bf(o[5]) << 16) | f2bf(o[4]);
            q.w = ((unsigned)f2bf(o[7]) << 16) | f2bf(o[6]);
            *(uint4*)(outb + (size_t)i * D + cl * 8) = q;
        }
    }
}

// ---------- launch ----------
extern "C" void kernel_launch(void* const* d_in, const int* in_sizes, int n_in,
                              void* d_out, int out_size, void* d_ws, size_t ws_size,
                              hipStream_t stream) {
    const float* x  = (const float*)d_in[0];
    const int*   ei = (const int*)d_in[1];   // [2, E] int32
    const float* W1 = (const float*)d_in[2];
    const float* b1 = (const float*)d_in[3];
    const float* W2 = (const float*)d_in[4];
    const float* b2 = (const float*)d_in[5];
    const float* W3 = (const float*)d_in[6];
    const float* b3 = (const float*)d_in[7];

    const int n = in_sizes[0] / 256;     // 50000
    const int E = in_sizes[1] / 2;       // 800000
    const int mpad = ((n + 127) / 128) * 128;  // 50048

    char* ws = (char*)d_ws;
    size_t off = 0;
    auto alloc = [&](size_t bytes) -> void* {
        void* p = ws + off;
        off += (bytes + 255) & ~(size_t)255;
        return p;
    };
    int* cz       = (int*)alloc((size_t)2 * n * 4);  // cnt | cursor (one memset)
    int* cnt      = cz;
    int* cursor   = cz + n;
    int* rs       = (int*)alloc((size_t)n * 4);
    float* dinv   = (float*)alloc((size_t)n * 4);
    int* bsum     = (int*)alloc(256 * 4);
    int* boff     = (int*)alloc(256 * 4);
    int* col      = (int*)alloc((size_t)E * 4);
    unsigned short* Wt = (unsigned short*)alloc((size_t)163840 * 2);
    unsigned short* W1t = Wt;
    unsigned short* W2t = Wt + 65536;
    unsigned short* W3t = Wt + 131072;
    unsigned short* bufA = (unsigned short*)alloc((size_t)mpad * 256 * 2);
    unsigned short* bufB = (unsigned short*)alloc((size_t)mpad * 256 * 2);
    (void)ws_size; (void)n_in; (void)out_size;

    const int* srcp = ei;
    const int* dstp = ei + E;
    const int gE = (E + 255) / 256;
    const int gN = (n + 255) / 256;

    hipMemsetAsync(cz, 0, (size_t)2 * n * 4, stream);

    k_count<<<gE, 256, 0, stream>>>(dstp, E, cnt);
    k_scan1<<<gN, 256, 0, stream>>>(cnt, n, rs, bsum);
    k_scan2<<<1, 256, 0, stream>>>(bsum, gN, boff);
    k_scan3<<<gN, 256, 0, stream>>>(cnt, n, boff, rs, dinv);
    k_scatter<<<gE, 256, 0, stream>>>(srcp, dstp, E, rs, cursor, col);

    k_cvt_x<<<(mpad * 64 + 255) / 256, 256, 0, stream>>>(x, bufA, n, mpad);
    k_cvt_w3<<<640, 256, 0, stream>>>(W1, W2, W3, Wt);

    const int gAgg = (n + 3) / 4;
    dim3 gg1(mpad / 128, 2);
    k_gemm<<<gg1, 256, 0, stream>>>(bufA, W1t, bufB, dinv, n, 256);
    k_agg<256, true, false><<<gAgg, 256, 0, stream>>>(bufB, rs, cnt, col, dinv, b1,
                                                      bufA, nullptr, n, n);
    k_gemm<<<gg1, 256, 0, stream>>>(bufA, W2t, bufB, dinv, n, 256);
    k_agg<256, true, false><<<gAgg, 256, 0, stream>>>(bufB, rs, cnt, col, dinv, b2,
                                                      bufA, nullptr, n, n);
    dim3 gg3(mpad / 128, 1);
    k_gemm<<<gg3, 256, 0, stream>>>(bufA, W3t, bufB, dinv, n, 128);
    k_agg<128, false, true><<<gAgg, 256, 0, stream>>>(bufB, rs, cnt, col, dinv, b3,
                                                      nullptr, (float*)d_out, n, n);
}

// Round 3
// 354.934 us; speedup vs baseline: 1.4645x; 1.1195x over previous
//
#include <hip/hip_runtime.h>
#include <stdint.h>

// ---------- helpers ----------
typedef short v8s __attribute__((ext_vector_type(8)));
typedef float v4f __attribute__((ext_vector_type(4)));
typedef float v2f __attribute__((ext_vector_type(2)));

__device__ inline float bf2f(unsigned short h) {
    union { unsigned u; float f; } c; c.u = ((unsigned)h) << 16; return c.f;
}
__device__ inline unsigned short f2bf(float f) {
    union { float f; unsigned u; } c; c.f = f;
    unsigned u = c.u;
    unsigned r = (u + 0x7FFFu + ((u >> 16) & 1u)) >> 16;  // RNE
    return (unsigned short)r;
}
__device__ inline void gl_lds16(const unsigned short* g, unsigned short* l) {
    __builtin_amdgcn_global_load_lds(
        (const __attribute__((address_space(1))) unsigned int*)(g),
        (__attribute__((address_space(3))) unsigned int*)(l), 16, 0, 0);
}

// ---------- fused preprocessing pass 1 ----------
// blocks [0,gE): edge count + sequence number (atomic return value)
// blocks [gE,gE+gX): x fp32 -> bf16 padded
// blocks [gE+gX,...): W1/W2/W3 -> transposed bf16
__global__ void k_pre1(const int* __restrict__ dst, int E,
                       int* __restrict__ cnt, int* __restrict__ seq,
                       const float* __restrict__ x, unsigned short* __restrict__ A,
                       int n, int mpad,
                       const float* __restrict__ W1, const float* __restrict__ W2,
                       const float* __restrict__ W3, unsigned short* __restrict__ Wt,
                       int gE, int gX) {
    int b = blockIdx.x;
    if (b < gE) {
        int e = b * 256 + threadIdx.x;
        if (e < E) seq[e] = atomicAdd(&cnt[dst[e]], 1);
    } else if (b < gE + gX) {
        int g = (b - gE) * 256 + threadIdx.x;  // one float4 group
        int total = mpad * 64;
        if (g >= total) return;
        int row = g >> 6;
        float4 v;
        if (row < n) v = ((const float4*)x)[(size_t)g];
        else v = make_float4(0.f, 0.f, 0.f, 0.f);
        ushort4 o;
        o.x = f2bf(v.x); o.y = f2bf(v.y); o.z = f2bf(v.z); o.w = f2bf(v.w);
        ((ushort4*)A)[(size_t)g] = o;
    } else {
        int idx = (b - gE - gX) * 256 + threadIdx.x;  // < 163840 exact
        const float* W; int base, N;
        if (idx < 65536)       { W = W1; base = 0;      N = 256; }
        else if (idx < 131072) { W = W2; base = 65536;  N = 256; }
        else                   { W = W3; base = 131072; N = 128; }
        int loc = idx - base;
        int nn = loc >> 8;   // K = 256
        int k = loc & 255;
        Wt[idx] = f2bf(W[(size_t)k * N + nn]);
    }
}

// ---------- scans ----------
__global__ void k_scan1(const int* __restrict__ cnt, int n, int* __restrict__ incl,
                        int* __restrict__ bsum) {
    __shared__ int sm[256];
    int t = threadIdx.x;
    int i = blockIdx.x * 256 + t;
    int v = (i < n) ? cnt[i] : 0;
    sm[t] = v; __syncthreads();
    for (int off = 1; off < 256; off <<= 1) {
        int add = (t >= off) ? sm[t - off] : 0;
        __syncthreads();
        sm[t] += add;
        __syncthreads();
    }
    if (i < n) incl[i] = sm[t];
    if (t == 255) bsum[blockIdx.x] = sm[255];
}

__global__ void k_scan2(const int* __restrict__ bsum, int nb, int* __restrict__ boff) {
    __shared__ int sm[256];
    int t = threadIdx.x;
    int v = (t < nb) ? bsum[t] : 0;
    sm[t] = v; __syncthreads();
    for (int off = 1; off < 256; off <<= 1) {
        int add = (t >= off) ? sm[t - off] : 0;
        __syncthreads();
        sm[t] += add;
        __syncthreads();
    }
    if (t < nb) boff[t] = sm[t] - v;  // exclusive
}

// inclusive->exclusive global scan; also computes dinv
__global__ void k_scan3(const int* __restrict__ cnt, int n, const int* __restrict__ boff,
                        int* __restrict__ rs, float* __restrict__ dinv) {
    int i = blockIdx.x * 256 + threadIdx.x;
    if (i < n) {
        int c = cnt[i];
        rs[i] = rs[i] + boff[blockIdx.x] - c;
        dinv[i] = rsqrtf((float)(c + 1));  // +1 self loop
    }
}

// ---------- scatter (atomic-free; position = rs[dst] + seq) ----------
__global__ void k_scatter2(const int* __restrict__ src, const int* __restrict__ dst,
                           const int* __restrict__ seq, int E,
                           const int* __restrict__ rs, int* __restrict__ col) {
    int e = blockIdx.x * 256 + threadIdx.x;
    if (e < E) col[rs[dst[e]] + seq[e]] = src[e];
}

// ---------- GEMM: Hs[m,n] = dinv[m] * sum_k A[m,k] * W[k,n] ----------
// launch_bounds(256,4): 4 waves/EU -> 4 blocks/CU (VGPR cap 128; acc 64 + frags 32 fits)
__launch_bounds__(256, 4)
__global__ void k_gemm(const unsigned short* __restrict__ A,
                       const unsigned short* __restrict__ Wt,
                       unsigned short* __restrict__ Hs,
                       const float* __restrict__ dinv, int n, int N) {
    __shared__ unsigned short sA[128 * 32];
    __shared__ unsigned short sB[128 * 32];
    const int t = threadIdx.x;
    const int lane = t & 63;
    const int wave = t >> 6;
    const int wm = wave >> 1, wn = wave & 1;
    const int m0 = blockIdx.x * 128;
    const int n0 = blockIdx.y * 128;

    v4f acc[4][4];
#pragma unroll
    for (int i = 0; i < 4; i++)
#pragma unroll
        for (int j = 0; j < 4; j++)
#pragma unroll
            for (int r = 0; r < 4; r++) acc[i][j][r] = 0.f;

    const int c0 = t, c1 = t + 256;
    const int r0 = c0 >> 2, kc0 = (c0 & 3) * 8;
    const int r1 = c1 >> 2, kc1 = (c1 & 3) * 8;
    const size_t aBase0 = (size_t)(m0 + r0) * 256 + kc0;
    const size_t aBase1 = (size_t)(m0 + r1) * 256 + kc1;
    const size_t bBase0 = (size_t)(n0 + r0) * 256 + kc0;
    const size_t bBase1 = (size_t)(n0 + r1) * 256 + kc1;

    const int q = lane >> 4;
    const int lm = lane & 15;

    for (int k0 = 0; k0 < 256; k0 += 32) {
        __syncthreads();
        gl_lds16(A + aBase0 + k0, &sA[c0 * 8]);
        gl_lds16(A + aBase1 + k0, &sA[c1 * 8]);
        gl_lds16(Wt + bBase0 + k0, &sB[c0 * 8]);
        gl_lds16(Wt + bBase1 + k0, &sB[c1 * 8]);
        __syncthreads();

        v8s afr[4], bfr[4];
#pragma unroll
        for (int i = 0; i < 4; i++) {
            int r = wm * 64 + i * 16 + lm;
            afr[i] = *(const v8s*)&sA[r * 32 + q * 8];
        }
#pragma unroll
        for (int j = 0; j < 4; j++) {
            int nn = wn * 64 + j * 16 + lm;
            bfr[j] = *(const v8s*)&sB[nn * 32 + q * 8];
        }
#pragma unroll
        for (int i = 0; i < 4; i++)
#pragma unroll
            for (int j = 0; j < 4; j++)
                acc[i][j] = __builtin_amdgcn_mfma_f32_16x16x32_bf16(afr[i], bfr[j],
                                                                    acc[i][j], 0, 0, 0);
    }

    // epilogue: C/D layout col=lane&15, row=(lane>>4)*4+reg
#pragma unroll
    for (int i = 0; i < 4; i++) {
        int mbase = m0 + wm * 64 + i * 16 + q * 4;
#pragma unroll
        for (int r = 0; r < 4; r++) {
            int m = mbase + r;
            float s = (m < n) ? dinv[m] : 0.f;
#pragma unroll
            for (int j = 0; j < 4; j++) {
                int colI = n0 + wn * 64 + j * 16 + lm;
                Hs[(size_t)m * N + colI] = f2bf(acc[i][j][r] * s);
            }
        }
    }
}

// ---------- aggregation: out[i] = act(dinv[i]*(sum_{nbr} hs[src] + hs[i]) + b) ----------
// 4-deep gather ILP (4 KiB in flight per wave), packed-f32 accumulate.
template <int D, bool RELU, bool F32OUT>
__launch_bounds__(256, 8)
__global__ void k_agg(const unsigned short* __restrict__ Hs,
                      const int* __restrict__ rs, const int* __restrict__ cnt,
                      const int* __restrict__ col, const float* __restrict__ dinv,
                      const float* __restrict__ bias,
                      unsigned short* __restrict__ outb, float* __restrict__ outf,
                      int n, int nzero) {
    constexpr int LPN = D / 8;     // lanes per neighbor row (32 for D=256, 16 for D=128)
    constexpr int NPG = 64 / LPN;  // neighbors per gather instruction (2 or 4)
    const int lane = threadIdx.x & 63;
    const int i = blockIdx.x * 4 + (threadIdx.x >> 6);
    if (i >= n) return;
    const int g = lane / LPN;      // neighbor slot within the gather
    const int cl = lane % LPN;     // channel chunk (8 channels each)

    v2f acc[4];
#pragma unroll
    for (int k = 0; k < 4; k++) acc[k] = (v2f){0.f, 0.f};

    // unpack bf16 pair as bit-ops -> packed f32 add (lo = u<<16, hi = u&0xffff0000)
    auto accq = [&](unsigned u, int k) {
        union { unsigned uu; float f; } lo, hi;
        lo.uu = u << 16;
        hi.uu = u & 0xffff0000u;
        v2f t; t[0] = lo.f; t[1] = hi.f;
        acc[k] += t;
    };
    auto acc16 = [&](uint4 q) { accq(q.x, 0); accq(q.y, 1); accq(q.z, 2); accq(q.w, 3); };

    const unsigned short* base = Hs + cl * 8;
    const int s = rs[i], deg = cnt[i];
    const int T = deg + 1;                       // self + neighbors
    const int Tpad = (T + NPG - 1) & ~(NPG - 1); // pad with zero-row nzero

    for (int b = 0; b < Tpad; b += 64) {
        int t = b + lane;
        int v;
        if (t == 0) v = i;                       // self loop
        else if (t <= deg) v = col[s + t - 1];   // coalesced chunk load
        else v = nzero;                          // zero row pad
        int lim = min(64, Tpad - b);
        int t2 = 0;
        for (; t2 + 4 * NPG <= lim; t2 += 4 * NPG) {
            int c0 = __shfl(v, t2 + 0 * NPG + g);
            int c1 = __shfl(v, t2 + 1 * NPG + g);
            int c2 = __shfl(v, t2 + 2 * NPG + g);
            int c3 = __shfl(v, t2 + 3 * NPG + g);
            uint4 q0 = *(const uint4*)(base + (size_t)c0 * D);
            uint4 q1 = *(const uint4*)(base + (size_t)c1 * D);
            uint4 q2 = *(const uint4*)(base + (size_t)c2 * D);
            uint4 q3 = *(const uint4*)(base + (size_t)c3 * D);
            acc16(q0); acc16(q1); acc16(q2); acc16(q3);
        }
        for (; t2 + NPG <= lim; t2 += NPG) {
            int c0 = __shfl(v, t2 + g);
            uint4 q0 = *(const uint4*)(base + (size_t)c0 * D);
            acc16(q0);
        }
    }

    // reduce across neighbor slots
#pragma unroll
    for (int off = LPN; off < 64; off <<= 1) {
#pragma unroll
        for (int k = 0; k < 4; k++) {
            acc[k][0] += __shfl_xor(acc[k][0], off);
            acc[k][1] += __shfl_xor(acc[k][1], off);
        }
    }

    if (g == 0) {  // lanes 0..LPN-1 write
        float di = dinv[i];
        float o[8];
#pragma unroll
        for (int k = 0; k < 4; k++) {
            o[2 * k + 0] = di * acc[k][0] + bias[cl * 8 + 2 * k + 0];
            o[2 * k + 1] = di * acc[k][1] + bias[cl * 8 + 2 * k + 1];
        }
        if (RELU) {
#pragma unroll
            for (int k = 0; k < 8; k++) o[k] = fmaxf(o[k], 0.f);
        }
        if constexpr (F32OUT) {
            float* p = outf + (size_t)i * D + cl * 8;
            *(float4*)p = make_float4(o[0], o[1], o[2], o[3]);
            *(float4*)(p + 4) = make_float4(o[4], o[5], o[6], o[7]);
        } else {
            uint4 q;
            q.x = ((unsigned)f2bf(o[1]) << 16) | f2bf(o[0]);
            q.y = ((unsigned)f2bf(o[3]) << 16) | f2bf(o[2]);
            q.z = ((unsigned)f2bf(o[5]) << 16) | f2bf(o[4]);
            q.w = ((unsigned)f2bf(o[7]) << 16) | f2bf(o[6]);
            *(uint4*)(outb + (size_t)i * D + cl * 8) = q;
        }
    }
}

// ---------- launch ----------
extern "C" void kernel_launch(void* const* d_in, const int* in_sizes, int n_in,
                              void* d_out, int out_size, void* d_ws, size_t ws_size,
                              hipStream_t stream) {
    const float* x  = (const float*)d_in[0];
    const int*   ei = (const int*)d_in[1];   // [2, E] int32
    const float* W1 = (const float*)d_in[2];
    const float* b1 = (const float*)d_in[3];
    const float* W2 = (const float*)d_in[4];
    const float* b2 = (const float*)d_in[5];
    const float* W3 = (const float*)d_in[6];
    const float* b3 = (const float*)d_in[7];

    const int n = in_sizes[0] / 256;     // 50000
    const int E = in_sizes[1] / 2;       // 800000
    const int mpad = ((n + 127) / 128) * 128;  // 50048

    char* ws = (char*)d_ws;
    size_t off = 0;
    auto alloc = [&](size_t bytes) -> void* {
        void* p = ws + off;
        off += (bytes + 255) & ~(size_t)255;
        return p;
    };
    int* cnt      = (int*)alloc((size_t)n * 4);
    int* rs       = (int*)alloc((size_t)n * 4);
    float* dinv   = (float*)alloc((size_t)n * 4);
    int* bsum     = (int*)alloc(256 * 4);
    int* boff     = (int*)alloc(256 * 4);
    int* seq      = (int*)alloc((size_t)E * 4);
    int* col      = (int*)alloc((size_t)E * 4);
    unsigned short* Wt = (unsigned short*)alloc((size_t)163840 * 2);
    unsigned short* W1t = Wt;
    unsigned short* W2t = Wt + 65536;
    unsigned short* W3t = Wt + 131072;
    unsigned short* bufA = (unsigned short*)alloc((size_t)mpad * 256 * 2);
    unsigned short* bufB = (unsigned short*)alloc((size_t)mpad * 256 * 2);
    (void)ws_size; (void)n_in; (void)out_size;

    const int* srcp = ei;
    const int* dstp = ei + E;
    const int gE = (E + 255) / 256;            // 3125
    const int gN = (n + 255) / 256;            // 196
    const int gX = (mpad * 64 + 255) / 256;    // 12512
    const int gW = 640;                        // 163840 / 256

    hipMemsetAsync(cnt, 0, (size_t)n * 4, stream);

    k_pre1<<<gE + gX + gW, 256, 0, stream>>>(dstp, E, cnt, seq, x, bufA, n, mpad,
                                             W1, W2, W3, Wt, gE, gX);
    k_scan1<<<gN, 256, 0, stream>>>(cnt, n, rs, bsum);
    k_scan2<<<1, 256, 0, stream>>>(bsum, gN, boff);
    k_scan3<<<gN, 256, 0, stream>>>(cnt, n, boff, rs, dinv);
    k_scatter2<<<gE, 256, 0, stream>>>(srcp, dstp, seq, E, rs, col);

    const int gAgg = (n + 3) / 4;
    dim3 gg1(mpad / 128, 2);
    k_gemm<<<gg1, 256, 0, stream>>>(bufA, W1t, bufB, dinv, n, 256);
    k_agg<256, true, false><<<gAgg, 256, 0, stream>>>(bufB, rs, cnt, col, dinv, b1,
                                                      bufA, nullptr, n, n);
    k_gemm<<<gg1, 256, 0, stream>>>(bufA, W2t, bufB, dinv, n, 256);
    k_agg<256, true, false><<<gAgg, 256, 0, stream>>>(bufB, rs, cnt, col, dinv, b2,
                                                      bufA, nullptr, n, n);
    dim3 gg3(mpad / 128, 1);
    k_gemm<<<gg3, 256, 0, stream>>>(bufA, W3t, bufB, dinv, n, 128);
    k_agg<128, false, true><<<gAgg, 256, 0, stream>>>(bufB, rs, cnt, col, dinv, b3,
                                                      nullptr, (float*)d_out, n, n);
}